// Round 6
// baseline (127.849 us; speedup 1.0000x reference)
//
#include <hip/hip_runtime.h>
#include <hip/hip_bf16.h>

// SeqOuterProductMean on MI355X — 2 kernels, no grid sync.
// K_A: LN + s1/s2 projections (blocks 0..383) || w3->bf16 cast (384..895).
// K_BC (one block pair per j): T_j[p*32+d] = sum_f s2[j,f]*w3c[p*32+d, f]
//   computed into LDS via broadcast-A MFMA, then
//   out[i, j*128+p] = sum_d s1[i,d]*T_j[p*32+d] + b3[p] via swapped-MFMA
//   (lane holds out[m0+l15][p0+quad*4+r] -> f32x4 full-line stores).
// Dependency B->C is local in j, so no grid-wide barrier is needed.

typedef __attribute__((ext_vector_type(8))) short short8;   // 8 x bf16
typedef __attribute__((ext_vector_type(4))) short bf16x4;   // 4 x bf16
typedef __attribute__((ext_vector_type(4))) float f32x4;

static __device__ __forceinline__ short f2bf(float f) {
    unsigned u = __float_as_uint(f);
    unsigned r = u + 0x7fffu + ((u >> 16) & 1u);   // round-to-nearest-even
    return (short)(r >> 16);
}

// ---------------------------------------------------------------------------
// K_A: LayerNorm + projections (blocks 0..383), w3 cast (blocks 384..895).
// ---------------------------------------------------------------------------
__global__ __launch_bounds__(256) void ln_proj_cast_kernel(
    const float* __restrict__ seq, const float* __restrict__ gamma,
    const float* __restrict__ beta, const float* __restrict__ w1,
    const float* __restrict__ b1, const float* __restrict__ w2,
    const float* __restrict__ b2, const float* __restrict__ w3,
    short* __restrict__ s1, short* __restrict__ s2, short* __restrict__ w3c,
    int L) {
    const int t = threadIdx.x;

    if (blockIdx.x >= L) {                 // ---- cast branch ----
        int i = (blockIdx.x - L) * 256 + t;
        w3c[i] = f2bf(w3[i]);
        return;
    }

    const int row = blockIdx.x;
    const int wv = t >> 6;      // wave 0..3
    const int ln = t & 63;      // lane 0..63

    __shared__ float wsum[4];
    __shared__ float xln[256];
    __shared__ float part[4][64];

    float v = seq[row * 256 + t];

    float s = v;
    #pragma unroll
    for (int off = 32; off > 0; off >>= 1) s += __shfl_down(s, off);
    if (ln == 0) wsum[wv] = s;
    __syncthreads();
    float mean = (wsum[0] + wsum[1] + wsum[2] + wsum[3]) * (1.0f / 256.0f);

    float c = v - mean;
    float cs = c * c;
    #pragma unroll
    for (int off = 32; off > 0; off >>= 1) cs += __shfl_down(cs, off);
    __syncthreads();
    if (ln == 0) wsum[wv] = cs;
    __syncthreads();
    float var = (wsum[0] + wsum[1] + wsum[2] + wsum[3]) * (1.0f / 256.0f);

    float xn = c * rsqrtf(var + 1e-5f) * gamma[t] + beta[t];
    xln[t] = xn;
    __syncthreads();

    const float* w = (ln < 32) ? (w1 + ln * 256) : (w2 + (ln - 32) * 256);
    const f32x4* wp = (const f32x4*)(w + wv * 64);
    const float* xs = &xln[wv * 64];
    float p = 0.0f;
    #pragma unroll
    for (int i = 0; i < 16; ++i) {
        f32x4 w4 = wp[i];
        p += xs[4*i + 0] * w4.x + xs[4*i + 1] * w4.y +
             xs[4*i + 2] * w4.z + xs[4*i + 3] * w4.w;
    }
    part[wv][ln] = p;
    __syncthreads();

    if (t < 64) {
        float r = part[0][t] + part[1][t] + part[2][t] + part[3][t];
        if (t < 32) { r += b1[t];      s1[row * 32 + t]        = f2bf(r); }
        else        { r += b2[t - 32]; s2[row * 32 + (t - 32)] = f2bf(r); }
    }
}

// ---------------------------------------------------------------------------
// K_BC: block bx -> j = bx>>1, m-split = bx&1 (rows split*192 .. +192).
// Phase 1: T_j (128 p-rows x 32 d, bf16, LDS row stride 40) via 64 MFMAs/wave.
// Phase 2: wave wv owns p-window wv*32; loops 12 m-tiles, 2 MFMAs each.
// ---------------------------------------------------------------------------
__global__ __launch_bounds__(256) void pair_fused_kernel(
    const short* __restrict__ s1, const short* __restrict__ s2,
    const short* __restrict__ w3c, const float* __restrict__ b3,
    float* __restrict__ out) {
    const int bx = blockIdx.x;
    const int j = bx >> 1;
    const int split = bx & 1;
    const int t = threadIdx.x;
    const int wv = t >> 6;
    const int ln = t & 63;
    const int l15 = ln & 15;
    const int quad = ln >> 4;
    const int k0 = quad * 8;

    __shared__ short Tlds[128 * 40];   // 10240 B, padded rows (80 B) vs 64 B

    // ---- Phase 1: T_j into LDS ----
    // Broadcast-A trick: every lane carries s2[j, k0..k0+7] as the B operand,
    // so all 16 m-columns of the MFMA result are identical; intrinsic-A rows
    // are w3c rows (flat n = p*32+d). Lane (quad,r) holds T_j[n0+quad*4+r].
    short8 s2frag = *(const short8*)(s2 + j * 32 + k0);
    #pragma unroll 4
    for (int i = 0; i < 64; ++i) {
        int n0 = (wv * 64 + i) * 16;
        short8 wfrag = *(const short8*)(w3c + (size_t)(n0 + l15) * 32 + k0);
        f32x4 acc = {0.0f, 0.0f, 0.0f, 0.0f};
        acc = __builtin_amdgcn_mfma_f32_16x16x32_bf16(wfrag, s2frag, acc, 0, 0, 0);
        if (l15 == 0) {
            int base = n0 + quad * 4;
            int p = base >> 5, d = base & 31;
            bf16x4 pv = { f2bf(acc.x), f2bf(acc.y), f2bf(acc.z), f2bf(acc.w) };
            *(bf16x4*)(&Tlds[p * 40 + d]) = pv;
        }
    }
    __syncthreads();

    // ---- Phase 2: out rows [split*192, split*192+192), cols j*128 + [0,128) ----
    const int pw = wv;                       // each wave owns one 32-wide p-window
    short8 bf0 = *(const short8*)(&Tlds[(pw * 32 + l15) * 40 + k0]);
    short8 bf1 = *(const short8*)(&Tlds[(pw * 32 + 16 + l15) * 40 + k0]);
    f32x4 bv0 = *(const f32x4*)(b3 + pw * 32 + quad * 4);
    f32x4 bv1 = *(const f32x4*)(b3 + pw * 32 + 16 + quad * 4);

    const size_t N = 49152;
    float* dbase = out + (size_t)(split * 192 + l15) * N + j * 128 + pw * 32 + quad * 4;

    #pragma unroll 3
    for (int mt = 0; mt < 12; ++mt) {
        int m0 = split * 192 + mt * 16;
        short8 af = *(const short8*)(s1 + (size_t)(m0 + l15) * 32 + k0);
        f32x4 acc0 = {0.0f, 0.0f, 0.0f, 0.0f};
        f32x4 acc1 = {0.0f, 0.0f, 0.0f, 0.0f};
        acc0 = __builtin_amdgcn_mfma_f32_16x16x32_bf16(bf0, af, acc0, 0, 0, 0);
        acc1 = __builtin_amdgcn_mfma_f32_16x16x32_bf16(bf1, af, acc1, 0, 0, 0);

        float* dp = dbase + (size_t)mt * 16 * N;
        *(f32x4*)dp        = acc0 + bv0;
        *(f32x4*)(dp + 16) = acc1 + bv1;
    }
}

// ---------------------------------------------------------------------------
extern "C" void kernel_launch(void* const* d_in, const int* in_sizes, int n_in,
                              void* d_out, int out_size, void* d_ws, size_t ws_size,
                              hipStream_t stream) {
    const float* seq   = (const float*)d_in[0];
    const float* gamma = (const float*)d_in[1];
    const float* beta  = (const float*)d_in[2];
    const float* w1    = (const float*)d_in[3];
    const float* b1    = (const float*)d_in[4];
    const float* w2    = (const float*)d_in[5];
    const float* b2    = (const float*)d_in[6];
    const float* w3    = (const float*)d_in[7];
    const float* b3    = (const float*)d_in[8];
    float* out = (float*)d_out;

    const int L = 384, H = 32, P = 128;

    char* ws = (char*)d_ws;
    short* s1  = (short*)(ws);                        // 384*32*2   = 24576
    short* s2  = (short*)(ws + 24576);                // 24576
    short* w3c = (short*)(ws + 49152);                // 131072*2   = 262144

    // K_A: LN + projections (blocks 0..383) + w3 cast (blocks 384..895)
    ln_proj_cast_kernel<<<L + (P * H * H) / 256, 256, 0, stream>>>(
        seq, gamma, beta, w1, b1, w2, b2, w3, s1, s2, w3c, L);

    // K_BC: 384 j x 2 m-splits
    pair_fused_kernel<<<L * 2, 256, 0, stream>>>(s1, s2, w3c, b3, out);
}

// Round 7
// 112.615 us; speedup vs baseline: 1.1353x; 1.1353x over previous
//
#include <hip/hip_runtime.h>
#include <hip/hip_bf16.h>

// SeqOuterProductMean on MI355X — R7 = R4 structure (best known, 113.1 us),
// K3 spread over 2x more blocks (grid 384x8, MITERS 3).
// T[j,p,d] = sum_f s2[j,f]*w3[p,d*32+f]          (GEMM2: M=384, N=4096,  K=32)
// pair[i, j*128+p] = sum_d s1[i,d]*T[j*128+p,d]  (GEMM3: M=384, N=49152, K=32)
// w3 flat [p][d*32+f] == [(p*32+d)][f] row-major -> GEMM2 B with no permute.
// GEMM2 out [384,4096] row-major == GEMM3 B [49152,32] row-major.
// Swapped-operand MFMA (C rows = n): lane stores 4 consecutive n -> f32x4
// full-line stores (2 per row per wave-iter = 128 B lines).

typedef __attribute__((ext_vector_type(8))) short short8;   // 8 x bf16
typedef __attribute__((ext_vector_type(4))) short bf16x4;   // 4 x bf16
typedef __attribute__((ext_vector_type(4))) float f32x4;

static __device__ __forceinline__ short f2bf(float f) {
    unsigned u = __float_as_uint(f);
    unsigned r = u + 0x7fffu + ((u >> 16) & 1u);   // round-to-nearest-even
    return (short)(r >> 16);
}

// ---------------------------------------------------------------------------
// K1: (blocks 0..L-1) LayerNorm + both H=32 projections, one block per row.
//     (blocks L..L+511) cast w3 (131072 floats) to bf16, 256 elems/block.
// ---------------------------------------------------------------------------
__global__ __launch_bounds__(256) void ln_proj_cast_kernel(
    const float* __restrict__ seq, const float* __restrict__ gamma,
    const float* __restrict__ beta, const float* __restrict__ w1,
    const float* __restrict__ b1, const float* __restrict__ w2,
    const float* __restrict__ b2, const float* __restrict__ w3,
    short* __restrict__ s1, short* __restrict__ s2, short* __restrict__ w3c,
    int L) {
    const int t = threadIdx.x;

    if (blockIdx.x >= L) {                 // ---- cast branch ----
        int i = (blockIdx.x - L) * 256 + t;
        w3c[i] = f2bf(w3[i]);
        return;
    }

    const int row = blockIdx.x;
    const int wv = t >> 6;      // wave 0..3
    const int ln = t & 63;      // lane 0..63

    __shared__ float wsum[4];
    __shared__ float xln[256];
    __shared__ float part[4][64];

    float v = seq[row * 256 + t];

    float s = v;
    #pragma unroll
    for (int off = 32; off > 0; off >>= 1) s += __shfl_down(s, off);
    if (ln == 0) wsum[wv] = s;
    __syncthreads();
    float mean = (wsum[0] + wsum[1] + wsum[2] + wsum[3]) * (1.0f / 256.0f);

    float c = v - mean;
    float cs = c * c;
    #pragma unroll
    for (int off = 32; off > 0; off >>= 1) cs += __shfl_down(cs, off);
    __syncthreads();
    if (ln == 0) wsum[wv] = cs;
    __syncthreads();
    float var = (wsum[0] + wsum[1] + wsum[2] + wsum[3]) * (1.0f / 256.0f);

    float xn = c * rsqrtf(var + 1e-5f) * gamma[t] + beta[t];
    xln[t] = xn;
    __syncthreads();

    const float* w = (ln < 32) ? (w1 + ln * 256) : (w2 + (ln - 32) * 256);
    const f32x4* wp = (const f32x4*)(w + wv * 64);
    const float* xs = &xln[wv * 64];
    float p = 0.0f;
    #pragma unroll
    for (int i = 0; i < 16; ++i) {
        f32x4 w4 = wp[i];
        p += xs[4*i + 0] * w4.x + xs[4*i + 1] * w4.y +
             xs[4*i + 2] * w4.z + xs[4*i + 3] * w4.w;
    }
    part[wv][ln] = p;
    __syncthreads();

    if (t < 64) {
        float r = part[0][t] + part[1][t] + part[2][t] + part[3][t];
        if (t < 32) { r += b1[t];      s1[row * 32 + t]        = f2bf(r); }
        else        { r += b2[t - 32]; s2[row * 32 + (t - 32)] = f2bf(r); }
    }
}

// ---------------------------------------------------------------------------
// K2: K=32 skinny GEMM, bf16 out: T[384 x 4096].
// ---------------------------------------------------------------------------
template <int MITERS>
__global__ __launch_bounds__(256, 4) void gemm_k32_bf16_kernel(
    const short* __restrict__ A, const short* __restrict__ B,
    short* __restrict__ D, int N) {
    const int lane = threadIdx.x & 63;
    const int wave = threadIdx.x >> 6;
    const int l15  = lane & 15;
    const int quad = lane >> 4;
    const int k0   = quad * 8;
    const int n0   = blockIdx.x * 64 + wave * 16;
    const int mbeg = blockIdx.y * (MITERS * 16);

    short8 bfrag = *reinterpret_cast<const short8*>(B + (size_t)(n0 + l15) * 32 + k0);

    const short* aptr = A + (size_t)(mbeg + l15) * 32 + k0;
    short* dptr = D + (size_t)(mbeg + l15) * N + n0 + quad * 4;
    const size_t dstep = (size_t)16 * N;

    short8 a_cur = *reinterpret_cast<const short8*>(aptr);
    #pragma unroll
    for (int it = 0; it < MITERS; ++it) {
        aptr += 16 * 32;
        short8 a_nxt;
        if (it + 1 < MITERS) a_nxt = *reinterpret_cast<const short8*>(aptr);

        f32x4 acc = {0.0f, 0.0f, 0.0f, 0.0f};
        acc = __builtin_amdgcn_mfma_f32_16x16x32_bf16(bfrag, a_cur, acc, 0, 0, 0);

        bf16x4 pv = { f2bf(acc.x), f2bf(acc.y), f2bf(acc.z), f2bf(acc.w) };
        *reinterpret_cast<bf16x4*>(dptr) = pv;
        dptr += dstep;
        a_cur = a_nxt;
    }
}

// ---------------------------------------------------------------------------
// K3: K=32 skinny GEMM, fp32 out + bias. Wave = 16 rows x 32 cols per iter
// (2 MFMAs sharing one A-frag) -> full 128 B line per row per iter.
// ---------------------------------------------------------------------------
template <int MITERS>
__global__ __launch_bounds__(256, 4) void gemm_k32_f32_kernel(
    const short* __restrict__ A, const short* __restrict__ B,
    float* __restrict__ D, const float* __restrict__ bias, int N) {
    const int lane = threadIdx.x & 63;
    const int wave = threadIdx.x >> 6;
    const int l15  = lane & 15;
    const int quad = lane >> 4;
    const int k0   = quad * 8;
    const int n0   = blockIdx.x * 128 + wave * 32;  // 32-wide n window per wave
    const int mbeg = blockIdx.y * (MITERS * 16);

    short8 bfrag0 = *reinterpret_cast<const short8*>(B + (size_t)(n0      + l15) * 32 + k0);
    short8 bfrag1 = *reinterpret_cast<const short8*>(B + (size_t)(n0 + 16 + l15) * 32 + k0);

    f32x4 bv0 = *reinterpret_cast<const f32x4*>(bias + ((n0      + quad * 4) & 127));
    f32x4 bv1 = *reinterpret_cast<const f32x4*>(bias + ((n0 + 16 + quad * 4) & 127));

    const short* aptr = A + (size_t)(mbeg + l15) * 32 + k0;
    float* dptr = D + (size_t)(mbeg + l15) * N + n0 + quad * 4;
    const size_t dstep = (size_t)16 * N;

    short8 a_cur = *reinterpret_cast<const short8*>(aptr);
    #pragma unroll
    for (int it = 0; it < MITERS; ++it) {
        aptr += 16 * 32;
        short8 a_nxt;
        if (it + 1 < MITERS) a_nxt = *reinterpret_cast<const short8*>(aptr);

        f32x4 acc0 = {0.0f, 0.0f, 0.0f, 0.0f};
        f32x4 acc1 = {0.0f, 0.0f, 0.0f, 0.0f};
        acc0 = __builtin_amdgcn_mfma_f32_16x16x32_bf16(bfrag0, a_cur, acc0, 0, 0, 0);
        acc1 = __builtin_amdgcn_mfma_f32_16x16x32_bf16(bfrag1, a_cur, acc1, 0, 0, 0);

        *reinterpret_cast<f32x4*>(dptr)      = acc0 + bv0;
        *reinterpret_cast<f32x4*>(dptr + 16) = acc1 + bv1;
        dptr += dstep;
        a_cur = a_nxt;
    }
}

// ---------------------------------------------------------------------------
extern "C" void kernel_launch(void* const* d_in, const int* in_sizes, int n_in,
                              void* d_out, int out_size, void* d_ws, size_t ws_size,
                              hipStream_t stream) {
    const float* seq   = (const float*)d_in[0];
    const float* gamma = (const float*)d_in[1];
    const float* beta  = (const float*)d_in[2];
    const float* w1    = (const float*)d_in[3];
    const float* b1    = (const float*)d_in[4];
    const float* w2    = (const float*)d_in[5];
    const float* b2    = (const float*)d_in[6];
    const float* w3    = (const float*)d_in[7];
    const float* b3    = (const float*)d_in[8];
    float* out = (float*)d_out;

    const int L = 384, H = 32, P = 128;
    const int N2 = P * H;        // 4096
    const int N3 = L * P;        // 49152

    char* ws = (char*)d_ws;
    short* s1  = (short*)(ws);                        // 384*32*2   = 24576
    short* s2  = (short*)(ws + 24576);                // 24576
    short* w3c = (short*)(ws + 49152);                // 131072*2   = 262144
    short* T   = (short*)(ws + 311296);               // 384*4096*2 = 3145728

    // K1: LN + projections (blocks 0..383) + w3 cast (blocks 384..895)
    ln_proj_cast_kernel<<<L + (P * H * H) / 256, 256, 0, stream>>>(
        seq, gamma, beta, w1, b1, w2, b2, w3, s1, s2, w3c, L);

    // K2: T[j, p*32+d] = sum_f s2[j,f] * w3c[(p*32+d), f]   (bf16 out)
    gemm_k32_bf16_kernel<3><<<dim3(N2 / 64, 8), 256, 0, stream>>>(s2, w3c, T, N2);

    // K3: pair[i, j*128+p] = sum_d s1[i,d] * T[(j*128+p), d] + b3[p]  (fp32 out)
    // grid: 384 n-blocks (128 cols each) x 8 m-chunks (48 rows -> 3 m-tiles)
    gemm_k32_f32_kernel<3><<<dim3(N3 / 128, 8), 256, 0, stream>>>(s1, T, out, b3, N3);
}